// Round 1
// baseline (1120.960 us; speedup 1.0000x reference)
//
#include <hip/hip_runtime.h>

// Problem constants (match the reference file)
#define NNODES 50000
#define NEDGES 800000
#define FIN    128
#define NREL   8
#define NB     64
#define H1D    64
#define H2D    128
#define BN_EPS 1e-5f

// ---------------------------------------------------------------------------
// Edge counting: cnt[(dst,rel)]++
__global__ __launch_bounds__(256) void count_edges_kernel(
    const int* __restrict__ dst, const int* __restrict__ et,
    int* __restrict__ cnt, int E)
{
    int e = blockIdx.x * 256 + threadIdx.x;
    if (e < E) atomicAdd(&cnt[dst[e] * NREL + et[e]], 1);
}

// cnt (int) -> inv (float) in place: 1/max(cnt,1)
__global__ __launch_bounds__(256) void inv_kernel(int* __restrict__ cnt_i,
                                                  float* __restrict__ invf, int n)
{
    int i = blockIdx.x * 256 + threadIdx.x;
    if (i < n) {
        int c = cnt_i[i];
        invf[i] = 1.0f / (float)(c > 1 ? c : 1);
    }
}

// ---------------------------------------------------------------------------
// GEMM1:  [N,128] @ [128, 9*64]  -> cols<512: h1t[N,512];  col-block 8: agg1[N,64]+b1
// B source: by<8 -> W1[by]  (stride 64), by==8 -> root1 (stride 64)
__global__ __launch_bounds__(256) void gemm1_kernel(
    const float* __restrict__ X, const float* __restrict__ W1,
    const float* __restrict__ root1, const float* __restrict__ b1,
    float* __restrict__ h1t, float* __restrict__ agg1, int Nn)
{
    __shared__ float As[32][68];   // [BK][BM+4] pad: write conflict 4-way only
    __shared__ float Bs[32][64];
    const int by = blockIdx.y;               // 0..8
    const int m0 = blockIdx.x * 64;
    const float* Bsrc = (by < 8) ? (W1 + (size_t)by * FIN * H1D) : root1;
    const int tid = threadIdx.x;
    const int tr = tid >> 4, tc = tid & 15;  // 16x16 threads, 4x4 micro-tile
    const int ak = tid & 31, am = tid >> 5;  // A-load: k=ak, 8 rows/pass
    const int bn = tid & 63, bk = tid >> 6;  // B-load: n=bn, 4 k/pass

    float acc[4][4] = {};
    for (int kc = 0; kc < FIN; kc += 32) {
#pragma unroll
        for (int i = 0; i < 8; ++i) {
            int row = m0 + am + i * 8;
            As[ak][am + i * 8] = (row < Nn) ? X[(size_t)row * FIN + kc + ak] : 0.f;
        }
#pragma unroll
        for (int i = 0; i < 8; ++i) {
            int k = bk + i * 4;
            Bs[k][bn] = Bsrc[(size_t)(kc + k) * 64 + bn];
        }
        __syncthreads();
#pragma unroll
        for (int k = 0; k < 32; ++k) {
            const float4 av = *reinterpret_cast<const float4*>(&As[k][tr * 4]);
            const float4 bv = *reinterpret_cast<const float4*>(&Bs[k][tc * 4]);
            acc[0][0] += av.x * bv.x; acc[0][1] += av.x * bv.y; acc[0][2] += av.x * bv.z; acc[0][3] += av.x * bv.w;
            acc[1][0] += av.y * bv.x; acc[1][1] += av.y * bv.y; acc[1][2] += av.y * bv.z; acc[1][3] += av.y * bv.w;
            acc[2][0] += av.z * bv.x; acc[2][1] += av.z * bv.y; acc[2][2] += av.z * bv.z; acc[2][3] += av.z * bv.w;
            acc[3][0] += av.w * bv.x; acc[3][1] += av.w * bv.y; acc[3][2] += av.w * bv.z; acc[3][3] += av.w * bv.w;
        }
        __syncthreads();
    }
#pragma unroll
    for (int i = 0; i < 4; ++i) {
        int row = m0 + tr * 4 + i;
        if (row >= Nn) break;
        int col = tc * 4;
        if (by < 8) {
            float4 v = make_float4(acc[i][0], acc[i][1], acc[i][2], acc[i][3]);
            *reinterpret_cast<float4*>(&h1t[(size_t)row * 512 + by * 64 + col]) = v;
        } else {
            float4 v = make_float4(acc[i][0] + b1[col], acc[i][1] + b1[col + 1],
                                   acc[i][2] + b1[col + 2], acc[i][3] + b1[col + 3]);
            *reinterpret_cast<float4*>(&agg1[(size_t)row * H1D + col]) = v;
        }
    }
}

// ---------------------------------------------------------------------------
// Edge pass 1: agg1[dst] += inv[(dst,rel)] * h1t[src][rel*64 + lane]
__global__ __launch_bounds__(256) void edge1_kernel(
    const int* __restrict__ src, const int* __restrict__ dst,
    const int* __restrict__ et, const float* __restrict__ inv,
    const float* __restrict__ h1t, float* __restrict__ agg1, int E)
{
    int e = blockIdx.x * 4 + (threadIdx.x >> 6);
    int lane = threadIdx.x & 63;
    if (e >= E) return;
    int s = src[e], t = dst[e], r = et[e];
    float w = inv[t * NREL + r];
    float v = h1t[(size_t)s * 512 + r * 64 + lane] * w;
    atomicAdd(&agg1[(size_t)t * H1D + lane], v);
}

// Edge pass 2: aggin2[dst][rel*64+lane] += inv[(dst,rel)] * relu(agg1[src][lane])
__global__ __launch_bounds__(256) void edge2_kernel(
    const int* __restrict__ src, const int* __restrict__ dst,
    const int* __restrict__ et, const float* __restrict__ inv,
    const float* __restrict__ agg1, float* __restrict__ aggin2, int E)
{
    int e = blockIdx.x * 4 + (threadIdx.x >> 6);
    int lane = threadIdx.x & 63;
    if (e >= E) return;
    int s = src[e], t = dst[e], r = et[e];
    float w = inv[t * NREL + r];
    float v = fmaxf(agg1[(size_t)s * H1D + lane], 0.f) * w;
    atomicAdd(&aggin2[(size_t)t * 512 + r * 64 + lane], v);
}

// ---------------------------------------------------------------------------
// GEMM2: A[n,k] = k<512 ? aggin2[n,k] : relu(agg1[n,k-512]);
//        B[k,c] = k<512 ? W2flat[k,c] : root2[k-512,c];   C = A@B + b2 -> agg2[N,128]
__global__ __launch_bounds__(256) void gemm2_kernel(
    const float* __restrict__ aggin2, const float* __restrict__ agg1,
    const float* __restrict__ W2, const float* __restrict__ root2,
    const float* __restrict__ b2, float* __restrict__ agg2, int Nn)
{
    __shared__ float As[32][68];
    __shared__ float Bs[32][64];
    const int by = blockIdx.y;               // 0..1
    const int m0 = blockIdx.x * 64;
    const int n0 = by * 64;
    const int tid = threadIdx.x;
    const int tr = tid >> 4, tc = tid & 15;
    const int ak = tid & 31, am = tid >> 5;
    const int bn = tid & 63, bk = tid >> 6;

    float acc[4][4] = {};
    for (int kc = 0; kc < 576; kc += 32) {
        if (kc < 512) {
#pragma unroll
            for (int i = 0; i < 8; ++i) {
                int row = m0 + am + i * 8;
                As[ak][am + i * 8] = (row < Nn) ? aggin2[(size_t)row * 512 + kc + ak] : 0.f;
            }
#pragma unroll
            for (int i = 0; i < 8; ++i) {
                int k = bk + i * 4;
                Bs[k][bn] = W2[(size_t)(kc + k) * H2D + n0 + bn];
            }
        } else {
#pragma unroll
            for (int i = 0; i < 8; ++i) {
                int row = m0 + am + i * 8;
                As[ak][am + i * 8] = (row < Nn) ? fmaxf(agg1[(size_t)row * H1D + (kc - 512) + ak], 0.f) : 0.f;
            }
#pragma unroll
            for (int i = 0; i < 8; ++i) {
                int k = bk + i * 4;
                Bs[k][bn] = root2[(size_t)(kc + k - 512) * H2D + n0 + bn];
            }
        }
        __syncthreads();
#pragma unroll
        for (int k = 0; k < 32; ++k) {
            const float4 av = *reinterpret_cast<const float4*>(&As[k][tr * 4]);
            const float4 bv = *reinterpret_cast<const float4*>(&Bs[k][tc * 4]);
            acc[0][0] += av.x * bv.x; acc[0][1] += av.x * bv.y; acc[0][2] += av.x * bv.z; acc[0][3] += av.x * bv.w;
            acc[1][0] += av.y * bv.x; acc[1][1] += av.y * bv.y; acc[1][2] += av.y * bv.z; acc[1][3] += av.y * bv.w;
            acc[2][0] += av.z * bv.x; acc[2][1] += av.z * bv.y; acc[2][2] += av.z * bv.z; acc[2][3] += av.z * bv.w;
            acc[3][0] += av.w * bv.x; acc[3][1] += av.w * bv.y; acc[3][2] += av.w * bv.z; acc[3][3] += av.w * bv.w;
        }
        __syncthreads();
    }
#pragma unroll
    for (int i = 0; i < 4; ++i) {
        int row = m0 + tr * 4 + i;
        if (row >= Nn) break;
        int col = n0 + tc * 4;
        float4 v = make_float4(acc[i][0] + b2[col], acc[i][1] + b2[col + 1],
                               acc[i][2] + b2[col + 2], acc[i][3] + b2[col + 3]);
        *reinterpret_cast<float4*>(&agg2[(size_t)row * H2D + col]) = v;
    }
}

// ---------------------------------------------------------------------------
// batch counts (float)
__global__ __launch_bounds__(256) void batchcnt_kernel(const int* __restrict__ batch,
                                                       float* __restrict__ cntb, int Nn)
{
    int n = blockIdx.x * 256 + threadIdx.x;
    if (n < Nn) atomicAdd(&cntb[batch[n]], 1.0f);
}

// mean/max pooling of relu(agg2), exploiting sorted batch: flush on segment change
__global__ __launch_bounds__(256) void pool_kernel(
    const float* __restrict__ agg2, const int* __restrict__ batch,
    float* __restrict__ psum, float* __restrict__ pmax, int Nn)
{
    int c = threadIdx.x & 127;
    int p = threadIdx.x >> 7;              // 0..1
    int n0 = blockIdx.x * 128;
    int nend = n0 + 128 < Nn ? n0 + 128 : Nn;
    float sum = 0.f, mx = 0.f;
    int cur = -1;
    for (int n = n0 + p; n < nend; n += 2) {
        int b = batch[n];
        float v = fmaxf(agg2[(size_t)n * H2D + c], 0.f);
        if (b != cur) {
            if (cur >= 0) {
                atomicAdd(&psum[cur * H2D + c], sum);
                atomicMax((int*)&pmax[cur * H2D + c], __float_as_int(mx));
            }
            cur = b; sum = 0.f; mx = 0.f;
        }
        sum += v; mx = fmaxf(mx, v);
    }
    if (cur >= 0) {
        atomicAdd(&psum[cur * H2D + c], sum);
        atomicMax((int*)&pmax[cur * H2D + c], __float_as_int(mx));
    }
}

// ---------------------------------------------------------------------------
// Whole MLP head in one block. out: pred[64*32] then emb[64*16].
__global__ __launch_bounds__(256) void head_kernel(
    const float* __restrict__ psum, const float* __restrict__ pmax,
    const float* __restrict__ cntb,
    const float* __restrict__ fc1_w, const float* __restrict__ fc1_b,
    const float* __restrict__ bn_g, const float* __restrict__ bn_b,
    const float* __restrict__ fc2_w, const float* __restrict__ fc2_b,
    const float* __restrict__ dec1_w, const float* __restrict__ dec1_b,
    const float* __restrict__ dec2_w, const float* __restrict__ dec2_b,
    float* __restrict__ out)
{
    __shared__ float gs[64 * 128];   // later reused: es[1024] @0, ds[4096] @1024
    __shared__ float zs[64 * 64];
    __shared__ float mu[64], var_[64];
    float* es = gs;
    float* ds = gs + 1024;
    const int t = threadIdx.x;

    for (int i = t; i < 64 * 128; i += 256) {
        int b = i >> 7;
        gs[i] = psum[i] / fmaxf(cntb[b], 1.f) + pmax[i];
    }
    __syncthreads();
    // z = g @ fc1_w + fc1_b   [64,64]
    for (int o = t; o < 4096; o += 256) {
        int r = o >> 6, cc = o & 63;
        float a = fc1_b[cc];
        for (int k = 0; k < 128; ++k) a += gs[r * 128 + k] * fc1_w[k * 64 + cc];
        zs[o] = a;
    }
    __syncthreads();
    if (t < 64) {
        float s = 0.f;
        for (int r = 0; r < 64; ++r) s += zs[r * 64 + t];
        float m = s * (1.f / 64.f);
        float v = 0.f;
        for (int r = 0; r < 64; ++r) { float d = zs[r * 64 + t] - m; v += d * d; }
        mu[t] = m; var_[t] = v * (1.f / 64.f);
    }
    __syncthreads();
    // BN + leaky
    for (int o = t; o < 4096; o += 256) {
        int cc = o & 63;
        float z = (zs[o] - mu[cc]) / sqrtf(var_[cc] + BN_EPS) * bn_g[cc] + bn_b[cc];
        zs[o] = (z > 0.f) ? z : 0.2f * z;
    }
    __syncthreads();
    // emb = zs @ fc2_w + fc2_b  [64,16]  (also write to out)
    for (int o = t; o < 1024; o += 256) {
        int r = o >> 4, cc = o & 15;
        float a = fc2_b[cc];
        for (int k = 0; k < 64; ++k) a += zs[r * 64 + k] * fc2_w[k * 16 + cc];
        es[o] = a;
        out[2048 + o] = a;
    }
    __syncthreads();
    // d = leaky(es @ dec1_w + dec1_b) [64,64]
    for (int o = t; o < 4096; o += 256) {
        int r = o >> 6, cc = o & 63;
        float a = dec1_b[cc];
        for (int k = 0; k < 16; ++k) a += es[r * 16 + k] * dec1_w[k * 64 + cc];
        ds[o] = (a > 0.f) ? a : 0.2f * a;
    }
    __syncthreads();
    // pred = ds @ dec2_w + dec2_b [64,32]
    for (int o = t; o < 2048; o += 256) {
        int r = o >> 5, cc = o & 31;
        float a = dec2_b[cc];
        for (int k = 0; k < 64; ++k) a += ds[r * 64 + k] * dec2_w[k * 32 + cc];
        out[o] = a;
    }
}

// ---------------------------------------------------------------------------
extern "C" void kernel_launch(void* const* d_in, const int* in_sizes, int n_in,
                              void* d_out, int out_size, void* d_ws, size_t ws_size,
                              hipStream_t stream)
{
    const float* x      = (const float*)d_in[0];
    const int*   eidx   = (const int*)d_in[1];
    const int*   etype  = (const int*)d_in[2];
    const int*   batch  = (const int*)d_in[3];
    const float* W1     = (const float*)d_in[4];
    const float* root1  = (const float*)d_in[5];
    const float* b1     = (const float*)d_in[6];
    const float* W2     = (const float*)d_in[7];
    const float* root2  = (const float*)d_in[8];
    const float* b2     = (const float*)d_in[9];
    const float* fc1_w  = (const float*)d_in[10];
    const float* fc1_b  = (const float*)d_in[11];
    const float* bn_g   = (const float*)d_in[12];
    const float* bn_b   = (const float*)d_in[13];
    const float* fc2_w  = (const float*)d_in[14];
    const float* fc2_b  = (const float*)d_in[15];
    const float* dec1_w = (const float*)d_in[16];
    const float* dec1_b = (const float*)d_in[17];
    const float* dec2_w = (const float*)d_in[18];
    const float* dec2_b = (const float*)d_in[19];
    float* out = (float*)d_out;

    const int* src = eidx;            // edge_index[0]
    const int* dst = eidx + NEDGES;   // edge_index[1]

    // Workspace carve-up (floats). Total ~142.5 MB.
    float* ws     = (float*)d_ws;
    float* h1t    = ws;                               // N*512 (reused as aggin2)
    float* agg1   = h1t  + (size_t)NNODES * 512;      // N*64
    float* agg2   = agg1 + (size_t)NNODES * H1D;      // N*128
    float* inv    = agg2 + (size_t)NNODES * H2D;      // N*8 (int cnt, then float)
    float* psum   = inv  + (size_t)NNODES * NREL;     // 64*128
    float* pmax   = psum + NB * H2D;                  // 64*128
    float* cntb   = pmax + NB * H2D;                  // 64

    // zero: cnt, pool buffers (psum,pmax,cntb contiguous)
    hipMemsetAsync(inv, 0, (size_t)NNODES * NREL * sizeof(int), stream);
    hipMemsetAsync(psum, 0, (2 * NB * H2D + NB) * sizeof(float), stream);

    count_edges_kernel<<<(NEDGES + 255) / 256, 256, 0, stream>>>(dst, etype, (int*)inv, NEDGES);
    inv_kernel<<<(NNODES * NREL + 255) / 256, 256, 0, stream>>>((int*)inv, inv, NNODES * NREL);

    dim3 g1((NNODES + 63) / 64, 9);
    gemm1_kernel<<<g1, 256, 0, stream>>>(x, W1, root1, b1, h1t, agg1, NNODES);

    edge1_kernel<<<(NEDGES + 3) / 4, 256, 0, stream>>>(src, dst, etype, inv, h1t, agg1, NEDGES);

    // h1t is dead now; reuse its region as aggin2 (zeroed first, stream-ordered)
    float* aggin2 = h1t;
    hipMemsetAsync(aggin2, 0, (size_t)NNODES * 512 * sizeof(float), stream);

    edge2_kernel<<<(NEDGES + 3) / 4, 256, 0, stream>>>(src, dst, etype, inv, agg1, aggin2, NEDGES);

    dim3 g2((NNODES + 63) / 64, 2);
    gemm2_kernel<<<g2, 256, 0, stream>>>(aggin2, agg1, W2, root2, b2, agg2, NNODES);

    batchcnt_kernel<<<(NNODES + 255) / 256, 256, 0, stream>>>(batch, cntb, NNODES);
    pool_kernel<<<(NNODES + 127) / 128, 256, 0, stream>>>(agg2, batch, psum, pmax, NNODES);

    head_kernel<<<1, 256, 0, stream>>>(psum, pmax, cntb, fc1_w, fc1_b, bn_g, bn_b,
                                       fc2_w, fc2_b, dec1_w, dec1_b, dec2_w, dec2_b, out);
}